// Round 18
// baseline (53.238 us; speedup 1.0000x reference)
//
#include <hip/hip_runtime.h>

// VQ-VAE vector quantizer, MI355X — v15: fat waves (2 token-sets / 64 tokens
// per wave), 4-wave blocks, 1 block/CU, double-buffered stage-early e-stream.
// Each (Ah,Al) LDS read now feeds 6 MFMAs (was 3) -> LDS traffic halved.
// score(t,k) = x_t . e_k - 0.5*||e_k||^2  (argmax == argmin distance)
// x.e = xh.eh + (xh.el' + xl'.eh)/2048, *_lo' = (v - fp16(v))*2048 as fp16.

typedef _Float16 f16;
typedef _Float16 f16x4 __attribute__((ext_vector_type(4)));
typedef _Float16 f16x8 __attribute__((ext_vector_type(8)));
typedef float f32x16 __attribute__((ext_vector_type(16)));

#define ND 128
#define NK 512
#define NHW 4096
#define LO_SCALE 2048.0f
#define LO_INV (1.0f / 2048.0f)

// workspace layout (bytes): e-split only
#define WS_EHI 0
#define WS_ELO 131072u
#define WS_ENS 262144u
#define WS_NEED 264192u

// ================================================================ prep ======
// 32 blocks x 256 thr: split e SWIZZLED (16B slot ^= code&15) + 0.5*||e||^2
__global__ __launch_bounds__(256) void vq_prep_e(const float* __restrict__ e,
                                                 f16* __restrict__ ehi, f16* __restrict__ elo,
                                                 float* __restrict__ ens) {
  const int tid = threadIdx.x;
  const int k0 = (int)blockIdx.x * 16;
  const int r = tid >> 4, dq16 = tid & 15;
  const int k = k0 + r;
  float ssum = 0.0f;
  #pragma unroll
  for (int hh = 0; hh < 2; ++hh) {
    const int dq = dq16 + 16 * hh;
    const float4 v = *(const float4*)(e + (size_t)k * ND + 4 * dq);
    ssum += v.x * v.x + v.y * v.y + v.z * v.z + v.w * v.w;
    float va[4] = {v.x, v.y, v.z, v.w};
    f16x4 hv, lv;
    #pragma unroll
    for (int j = 0; j < 4; ++j) {
      const f16 h = (f16)va[j];
      hv[j] = h;
      lv[j] = (f16)((va[j] - (float)h) * LO_SCALE);
    }
    const int sl = (dq >> 1) ^ (k & 15);            // 16B-slot swizzle
    const size_t off = (size_t)k * ND + sl * 8 + (dq & 1) * 4;
    *(f16x4*)(ehi + off) = hv;
    *(f16x4*)(elo + off) = lv;
  }
  #pragma unroll
  for (int m = 1; m < 16; m <<= 1) ssum += __shfl_xor(ssum, m, 64);
  if (dq16 == 0) ens[k] = 0.5f * ssum;
}

// =============================================================== score ======
// grid 256 x 256 thr (4 waves, 1 block/CU). Wave w owns 64 tokens
// (sets: w*64+l31 and +32). e streams via double-buffered 64-code chunks,
// staged BEFORE compute (drain at end-of-iteration barrier finds data landed).
__global__ __launch_bounds__(256, 1) void vq_score(const float* __restrict__ x,
                                                   const f16* __restrict__ ehi,
                                                   const f16* __restrict__ elo,
                                                   const float* __restrict__ ens,
                                                   const float* __restrict__ e32,
                                                   float* __restrict__ out) {
  __shared__ f16 eh_s[2][64 * 128];   // 2 x 16KB [buf][code*128 + swz slot]
  __shared__ f16 el_s[2][64 * 128];   // 2 x 16KB
  __shared__ float ens_s[NK];         // 2KB                      (total 66KB)

  const int tid = threadIdx.x;        // 0..255
  const int w = tid >> 6;             // wave 0..3
  const int lane = tid & 63;
  const int l31 = lane & 31;
  const int half = lane >> 5;
  const int T0 = (int)blockIdx.x * 256;
  const int tok0 = T0 + w * 64 + l31;     // set-0 token
  const int tok1 = tok0 + 32;             // set-1 token
  const int bb = T0 >> 12;                // block never crosses batch b
  const int hw0 = tok0 & 4095;
  const int hw1 = tok1 & 4095;
  const int sbase = l31 & 15;         // swizzle key (== code&15 for row l31)

  // prologue: stage chunk 0 into buf0 (zero staging VGPRs)
  #pragma unroll
  for (int p = 0; p < 4; ++p) {
    __builtin_amdgcn_global_load_lds(ehi + p * 2048 + tid * 8, &eh_s[0][p * 2048 + tid * 8], 16, 0, 0);
    __builtin_amdgcn_global_load_lds(elo + p * 2048 + tid * 8, &el_s[0][p * 2048 + tid * 8], 16, 0, 0);
  }

  // x: direct strided-coalesced NCHW loads + in-register fp16 split, both sets
  f16x8 B0h[8], B0l[8], B1h[8], B1l[8];
  {
    const float* xb0 = x + (size_t)bb * ND * NHW + hw0;
    const float* xb1 = x + (size_t)bb * ND * NHW + hw1;
    #pragma unroll
    for (int ks = 0; ks < 8; ++ks) {
      const int oct = 2 * ks + half;
      #pragma unroll
      for (int j = 0; j < 8; ++j) {
        const float v0 = xb0[(size_t)(oct * 8 + j) * NHW];
        const float v1 = xb1[(size_t)(oct * 8 + j) * NHW];
        const f16 h0 = (f16)v0;
        const f16 h1 = (f16)v1;
        B0h[ks][j] = h0;
        B0l[ks][j] = (f16)((v0 - (float)h0) * LO_SCALE);
        B1h[ks][j] = h1;
        B1l[ks][j] = (f16)((v1 - (float)h1) * LO_SCALE);
      }
    }
  }
  ens_s[tid] = ens[tid];
  ens_s[tid + 256] = ens[tid + 256];
  __syncthreads();   // drains chunk-0 stage + x loads

  float bv0 = -3.0e38f, bv1 = -3.0e38f;
  int bi0 = 0, bi1 = 0;

  for (int c = 0; c < 8; ++c) {
    const int cur = c & 1;
    if (c < 7) {                      // issue next-chunk stage FIRST
      const f16* gh = ehi + (c + 1) * 8192;
      const f16* gl = elo + (c + 1) * 8192;
      f16* dh = &eh_s[cur ^ 1][0];
      f16* dl = &el_s[cur ^ 1][0];
      #pragma unroll
      for (int p = 0; p < 4; ++p) {
        __builtin_amdgcn_global_load_lds(gh + p * 2048 + tid * 8, dh + p * 2048 + tid * 8, 16, 0, 0);
        __builtin_amdgcn_global_load_lds(gl + p * 2048 + tid * 8, dl + p * 2048 + tid * 8, 16, 0, 0);
      }
    }
    // compute current chunk while next-chunk loads are in flight
    #pragma unroll
    for (int cg = 0; cg < 2; ++cg) {
      const int r = cg * 32 + l31;              // lane's code row in chunk (A)
      const f16* ah = &eh_s[cur][r * 128];
      const f16* al = &el_s[cur][r * 128];
      f32x16 a1_0 = {}, a2_0 = {}, a1_1 = {}, a2_1 = {};
      #pragma unroll
      for (int ks = 0; ks < 8; ++ks) {
        const int sl = ((2 * ks + half) ^ sbase) * 8;
        const f16x8 Ah = *(const f16x8*)(ah + sl);
        const f16x8 Al = *(const f16x8*)(al + sl);
        a2_0 = __builtin_amdgcn_mfma_f32_32x32x16_f16(Al, B0h[ks], a2_0, 0, 0, 0);
        a2_1 = __builtin_amdgcn_mfma_f32_32x32x16_f16(Al, B1h[ks], a2_1, 0, 0, 0);
        a1_0 = __builtin_amdgcn_mfma_f32_32x32x16_f16(Ah, B0h[ks], a1_0, 0, 0, 0);
        a1_1 = __builtin_amdgcn_mfma_f32_32x32x16_f16(Ah, B1h[ks], a1_1, 0, 0, 0);
        a2_0 = __builtin_amdgcn_mfma_f32_32x32x16_f16(Ah, B0l[ks], a2_0, 0, 0, 0);
        a2_1 = __builtin_amdgcn_mfma_f32_32x32x16_f16(Ah, B1l[ks], a2_1, 0, 0, 0);
      }
      // bias rows for this lane: rowr = (rr&3) + 8*(rr>>2) + 4*half
      const int kb = c * 64 + cg * 32 + 4 * half;
      const float4 b0 = *(const float4*)&ens_s[kb + 0];
      const float4 b1 = *(const float4*)&ens_s[kb + 8];
      const float4 b2 = *(const float4*)&ens_s[kb + 16];
      const float4 b3 = *(const float4*)&ens_s[kb + 24];
      const float bias[16] = {b0.x, b0.y, b0.z, b0.w, b1.x, b1.y, b1.z, b1.w,
                              b2.x, b2.y, b2.z, b2.w, b3.x, b3.y, b3.z, b3.w};
      #pragma unroll
      for (int rr = 0; rr < 16; ++rr) {
        const int code = kb + (rr & 3) + 8 * (rr >> 2);
        const float s0 = a1_0[rr] + a2_0[rr] * LO_INV - bias[rr];
        const float s1 = a1_1[rr] + a2_1[rr] * LO_INV - bias[rr];
        if (s0 > bv0) { bv0 = s0; bi0 = code; }  // ascending code: > keeps lowest
        if (s1 > bv1) { bv1 = s1; bi1 = code; }
      }
    }
    __syncthreads();   // next chunk staged (drain lands after compute)
  }

  // merge across lane-halves (same token for lane ^ 32)
  {
    const float o0 = __shfl_xor(bv0, 32, 64);
    const int i0 = __shfl_xor(bi0, 32, 64);
    if (o0 > bv0 || (o0 == bv0 && i0 < bi0)) { bv0 = o0; bi0 = i0; }
    const float o1 = __shfl_xor(bv1, 32, 64);
    const int i1 = __shfl_xor(bi1, 32, 64);
    if (o1 > bv1 || (o1 == bv1 && i1 < bi1)) { bv1 = o1; bi1 = i1; }
  }

  // fused output write: lane covers tok0 & tok1, d-range half*64..+64
  {
    const float* er0 = e32 + (size_t)bi0 * ND + half * 64;
    const float* er1 = e32 + (size_t)bi1 * ND + half * 64;
    float* ob0 = out + (size_t)bb * ND * NHW + (size_t)(half * 64) * NHW + hw0;
    float* ob1 = out + (size_t)bb * ND * NHW + (size_t)(half * 64) * NHW + hw1;
    #pragma unroll
    for (int j4 = 0; j4 < 16; ++j4) {
      const float4 e0 = *(const float4*)(er0 + j4 * 4);
      const float4 e1 = *(const float4*)(er1 + j4 * 4);
      ob0[(size_t)(j4 * 4 + 0) * NHW] = e0.x;
      ob0[(size_t)(j4 * 4 + 1) * NHW] = e0.y;
      ob0[(size_t)(j4 * 4 + 2) * NHW] = e0.z;
      ob0[(size_t)(j4 * 4 + 3) * NHW] = e0.w;
      ob1[(size_t)(j4 * 4 + 0) * NHW] = e1.x;
      ob1[(size_t)(j4 * 4 + 1) * NHW] = e1.y;
      ob1[(size_t)(j4 * 4 + 2) * NHW] = e1.z;
      ob1[(size_t)(j4 * 4 + 3) * NHW] = e1.w;
    }
  }
}

// ======================================================== fp32 fallback =====
__global__ __launch_bounds__(128) void vq_enorm(const float* __restrict__ e,
                                                float* __restrict__ ensw) {
  const int k = blockIdx.x;
  const int d = threadIdx.x;
  const float v = e[k * ND + d];
  float s = v * v;
  #pragma unroll
  for (int off = 32; off > 0; off >>= 1) s += __shfl_down(s, off, 64);
  __shared__ float tmp[2];
  if ((d & 63) == 0) tmp[d >> 6] = s;
  __syncthreads();
  if (d == 0) ensw[k] = tmp[0] + tmp[1];
}

__global__ __launch_bounds__(256, 2) void vq_main_f32(const float* __restrict__ x,
                                                      const float* __restrict__ e,
                                                      const float* __restrict__ ensw,
                                                      float* __restrict__ out) {
  __shared__ float xs[ND][64];
  __shared__ float esh[ND][64];
  __shared__ float enh[NK];
  __shared__ float red_v[64][17];
  __shared__ int red_i[64][17];
  __shared__ int bidx[64];
  const int tid = threadIdx.x;
  const int b = blockIdx.x >> 6;
  const int hw0 = (blockIdx.x & 63) * 64;
  const float* xb = x + ((size_t)b * ND) * NHW;
  #pragma unroll
  for (int i = 0; i < 8; ++i) {
    const int f = tid + 256 * i;
    const int d = f >> 4, t4 = f & 15;
    const float4 v = *(const float4*)(xb + (size_t)d * NHW + hw0 + 4 * t4);
    *(float4*)&xs[d][4 * t4] = v;
  }
  #pragma unroll
  for (int i = 0; i < 2; ++i) enh[tid + 256 * i] = ensw[tid + 256 * i];
  const int t4 = tid & 15, m = tid >> 4;
  float bvv[4] = {-3.0e38f, -3.0e38f, -3.0e38f, -3.0e38f};
  int bii[4] = {0, 0, 0, 0};
  for (int kc = 0; kc < NK / 64; ++kc) {
    __syncthreads();
    #pragma unroll
    for (int i = 0; i < 8; ++i) {
      const int f = tid + 256 * i;
      const int kk = f & 63, dq = f >> 6;
      const float4 v = *(const float4*)(e + (size_t)(kc * 64 + kk) * ND + 4 * dq);
      esh[4 * dq + 0][kk] = v.x; esh[4 * dq + 1][kk] = v.y;
      esh[4 * dq + 2][kk] = v.z; esh[4 * dq + 3][kk] = v.w;
    }
    __syncthreads();
    float acc[4][4];
    #pragma unroll
    for (int a = 0; a < 4; ++a)
      #pragma unroll
      for (int cc = 0; cc < 4; ++cc) acc[a][cc] = 0.0f;
    #pragma unroll 8
    for (int d = 0; d < ND; ++d) {
      const float4 xv = *(const float4*)&xs[d][4 * t4];
      const float4 ev = *(const float4*)&esh[d][4 * m];
      const float xa[4] = {xv.x, xv.y, xv.z, xv.w};
      const float ea[4] = {ev.x, ev.y, ev.z, ev.w};
      #pragma unroll
      for (int a = 0; a < 4; ++a)
        #pragma unroll
        for (int cc = 0; cc < 4; ++cc) acc[a][cc] = fmaf(xa[a], ea[cc], acc[a][cc]);
    }
    const int kbase = kc * 64 + 4 * m;
    #pragma unroll
    for (int cc = 0; cc < 4; ++cc) {
      const float bias = 0.5f * enh[kbase + cc];
      const int kg = kbase + cc;
      #pragma unroll
      for (int a = 0; a < 4; ++a) {
        const float s = acc[a][cc] - bias;
        if (s > bvv[a] || (s == bvv[a] && kg < bii[a])) { bvv[a] = s; bii[a] = kg; }
      }
    }
  }
  #pragma unroll
  for (int a = 0; a < 4; ++a) { red_v[4 * t4 + a][m] = bvv[a]; red_i[4 * t4 + a][m] = bii[a]; }
  __syncthreads();
  if (tid < 64) {
    float v = red_v[tid][0]; int ix = red_i[tid][0];
    #pragma unroll
    for (int j = 1; j < 16; ++j) {
      const float vj = red_v[tid][j]; const int ij = red_i[tid][j];
      if (vj > v || (vj == v && ij < ix)) { v = vj; ix = ij; }
    }
    bidx[tid] = ix;
  }
  __syncthreads();
  const int t = tid & 63, dgg = tid >> 6;
  const float* er = e + (size_t)bidx[t] * ND;
  float* ob = out + ((size_t)b * ND) * NHW + hw0 + t;
  #pragma unroll
  for (int i = 0; i < 32; ++i) ob[(size_t)(dgg * 32 + i) * NHW] = er[dgg * 32 + i];
}

// --------------------------------------------------------------- launch -----
extern "C" void kernel_launch(void* const* d_in, const int* in_sizes, int n_in,
                              void* d_out, int out_size, void* d_ws, size_t ws_size,
                              hipStream_t stream) {
  const float* x = (const float*)d_in[0];
  const float* e = (const float*)d_in[1];
  float* out = (float*)d_out;
  char* ws = (char*)d_ws;

  if (ws_size >= WS_NEED) {
    f16* ehi = (f16*)(ws + WS_EHI);
    f16* elo = (f16*)(ws + WS_ELO);
    float* ens = (float*)(ws + WS_ENS);
    vq_prep_e<<<32, 256, 0, stream>>>(e, ehi, elo, ens);
    vq_score<<<256, 256, 0, stream>>>(x, ehi, elo, ens, e, out);
  } else {
    float* ensw = (float*)d_ws;
    vq_enorm<<<NK, 128, 0, stream>>>(e, ensw);
    vq_main_f32<<<16 * 64, 256, 0, stream>>>(x, e, ensw, out);
  }
}

// Round 19
// 44.243 us; speedup vs baseline: 1.2033x; 1.2033x over previous
//
#include <hip/hip_runtime.h>

// VQ-VAE vector quantizer, MI355X — v16: v11 + T3/T4 counted-vmcnt pipeline.
// Raw s_barrier + s_waitcnt vmcnt(8) (never 0 in-loop): chunk c+2 stages while
// c+1 is awaited, loads stay in flight ACROSS barriers (m201/T4 pattern).
// Block = 128 tokens x ALL 512 codes, 256 thr / 4 waves, grid 512.
// score(t,k) = x_t . e_k - 0.5*||e_k||^2  (argmax == argmin distance)
// x.e = xh.eh + (xh.el' + xl'.eh)/2048, *_lo' = (v - fp16(v))*2048 as fp16.

typedef _Float16 f16;
typedef _Float16 f16x4 __attribute__((ext_vector_type(4)));
typedef _Float16 f16x8 __attribute__((ext_vector_type(8)));
typedef float f32x16 __attribute__((ext_vector_type(16)));

#define ND 128
#define NK 512
#define NHW 4096
#define LO_SCALE 2048.0f
#define LO_INV (1.0f / 2048.0f)

// workspace layout (bytes): e-split only
#define WS_EHI 0
#define WS_ELO 131072u
#define WS_ENS 262144u
#define WS_NEED 264192u

// ================================================================ prep ======
// 32 blocks x 256 thr: split e SWIZZLED (16B slot ^= code&15) + 0.5*||e||^2
__global__ __launch_bounds__(256) void vq_prep_e(const float* __restrict__ e,
                                                 f16* __restrict__ ehi, f16* __restrict__ elo,
                                                 float* __restrict__ ens) {
  const int tid = threadIdx.x;
  const int k0 = (int)blockIdx.x * 16;
  const int r = tid >> 4, dq16 = tid & 15;
  const int k = k0 + r;
  float ssum = 0.0f;
  #pragma unroll
  for (int hh = 0; hh < 2; ++hh) {
    const int dq = dq16 + 16 * hh;
    const float4 v = *(const float4*)(e + (size_t)k * ND + 4 * dq);
    ssum += v.x * v.x + v.y * v.y + v.z * v.z + v.w * v.w;
    float va[4] = {v.x, v.y, v.z, v.w};
    f16x4 hv, lv;
    #pragma unroll
    for (int j = 0; j < 4; ++j) {
      const f16 h = (f16)va[j];
      hv[j] = h;
      lv[j] = (f16)((va[j] - (float)h) * LO_SCALE);
    }
    const int sl = (dq >> 1) ^ (k & 15);            // 16B-slot swizzle
    const size_t off = (size_t)k * ND + sl * 8 + (dq & 1) * 4;
    *(f16x4*)(ehi + off) = hv;
    *(f16x4*)(elo + off) = lv;
  }
  #pragma unroll
  for (int m = 1; m < 16; m <<= 1) ssum += __shfl_xor(ssum, m, 64);
  if (dq16 == 0) ens[k] = 0.5f * ssum;
}

// =============================================================== score ======
// grid 512 x 256 thr (4 waves). Double-buffered chunks with COUNTED vmcnt:
//   iter c: [buf(cur)=chunk c ready] compute(c) ; s_barrier (reads done) ;
//           stage(c+2 -> buf(cur)) ; s_waitcnt vmcnt(8)  (c+1 landed) ;
//           s_barrier ; swap.
// vmcnt never drains to 0 in the main loop (T4).
__global__ __launch_bounds__(256) void vq_score(const float* __restrict__ x,
                                                const f16* __restrict__ ehi,
                                                const f16* __restrict__ elo,
                                                const float* __restrict__ ens,
                                                const float* __restrict__ e32,
                                                float* __restrict__ out) {
  __shared__ f16 eh_s[2][64 * 128];   // 2 x 16KB [buf][code*128 + swz slot]
  __shared__ f16 el_s[2][64 * 128];   // 2 x 16KB
  __shared__ float ens_s[NK];         // 2KB                      (total 66KB)

  const int tid = threadIdx.x;        // 0..255
  const int w = tid >> 6;             // wave 0..3
  const int lane = tid & 63;
  const int l31 = lane & 31;
  const int half = lane >> 5;
  const int T0 = (int)blockIdx.x * 128;
  const int tok = T0 + w * 32 + l31;  // this lane's token
  const int bb = tok >> 12;
  const int hw = tok & 4095;
  const int sbase = l31 & 15;         // swizzle key (== code&15 for row l31)

  // ens first: its ds_write forces a wait that drains only these 2 loads
  ens_s[tid] = ens[tid];
  ens_s[tid + 256] = ens[tid + 256];

  // x loads (oldest large batch) + in-register fp16 split, fragment order
  f16x8 Bh[8], Bl[8];
  {
    const float* xb = x + (size_t)bb * ND * NHW + hw;
    #pragma unroll
    for (int ks = 0; ks < 8; ++ks) {
      const int oct = 2 * ks + half;
      #pragma unroll
      for (int j = 0; j < 8; ++j) {
        const float v = xb[(size_t)(oct * 8 + j) * NHW];
        const f16 hv = (f16)v;
        Bh[ks][j] = hv;
        Bl[ks][j] = (f16)((v - (float)hv) * LO_SCALE);
      }
    }
  }

  // stage chunk 0 -> buf0, chunk 1 -> buf1 (8 gload_lds ops per chunk)
  #pragma unroll
  for (int p = 0; p < 4; ++p) {
    __builtin_amdgcn_global_load_lds(ehi + p * 2048 + tid * 8, &eh_s[0][p * 2048 + tid * 8], 16, 0, 0);
    __builtin_amdgcn_global_load_lds(elo + p * 2048 + tid * 8, &el_s[0][p * 2048 + tid * 8], 16, 0, 0);
  }
  #pragma unroll
  for (int p = 0; p < 4; ++p) {
    __builtin_amdgcn_global_load_lds(ehi + 8192 + p * 2048 + tid * 8, &eh_s[1][p * 2048 + tid * 8], 16, 0, 0);
    __builtin_amdgcn_global_load_lds(elo + 8192 + p * 2048 + tid * 8, &el_s[1][p * 2048 + tid * 8], 16, 0, 0);
  }

  // chunk0 landed (chunk1's 8 ops may remain in flight)
  asm volatile("s_waitcnt vmcnt(8)" ::: "memory");
  __builtin_amdgcn_sched_barrier(0);
  __builtin_amdgcn_s_barrier();

  float bv = -3.0e38f;
  int bi = 0;

  for (int c = 0; c < 8; ++c) {
    const int cur = c & 1;
    // ---- compute chunk c from buf[cur] ----
    #pragma unroll
    for (int cg = 0; cg < 2; ++cg) {
      const int r = cg * 32 + l31;              // lane's code row in chunk (A)
      const f16* ah = &eh_s[cur][r * 128];
      const f16* al = &el_s[cur][r * 128];
      f32x16 a1 = {}, a2 = {};
      __builtin_amdgcn_s_setprio(1);
      #pragma unroll
      for (int ks = 0; ks < 8; ++ks) {
        const int sl = ((2 * ks + half) ^ sbase) * 8;
        const f16x8 Ah = *(const f16x8*)(ah + sl);
        const f16x8 Al = *(const f16x8*)(al + sl);
        a2 = __builtin_amdgcn_mfma_f32_32x32x16_f16(Al, Bh[ks], a2, 0, 0, 0);
        a1 = __builtin_amdgcn_mfma_f32_32x32x16_f16(Ah, Bh[ks], a1, 0, 0, 0);
        a2 = __builtin_amdgcn_mfma_f32_32x32x16_f16(Ah, Bl[ks], a2, 0, 0, 0);
      }
      __builtin_amdgcn_s_setprio(0);
      // bias rows for this lane: rowr = (rr&3) + 8*(rr>>2) + 4*half
      const int kb = c * 64 + cg * 32 + 4 * half;
      const float4 b0 = *(const float4*)&ens_s[kb + 0];
      const float4 b1 = *(const float4*)&ens_s[kb + 8];
      const float4 b2 = *(const float4*)&ens_s[kb + 16];
      const float4 b3 = *(const float4*)&ens_s[kb + 24];
      const float bias[16] = {b0.x, b0.y, b0.z, b0.w, b1.x, b1.y, b1.z, b1.w,
                              b2.x, b2.y, b2.z, b2.w, b3.x, b3.y, b3.z, b3.w};
      #pragma unroll
      for (int rr = 0; rr < 16; ++rr) {
        const float s = a1[rr] + a2[rr] * LO_INV - bias[rr];
        const int code = kb + (rr & 3) + 8 * (rr >> 2);
        if (s > bv) { bv = s; bi = code; }  // ascending code: > keeps lowest
      }
    }
    // ---- pipeline boundary: reads of buf[cur] done -> restage it ----
    __builtin_amdgcn_s_barrier();           // all waves done reading buf[cur]
    if (c + 2 <= 7) {
      const f16* gh = ehi + (c + 2) * 8192;
      const f16* gl = elo + (c + 2) * 8192;
      f16* dh = &eh_s[cur][0];
      f16* dl = &el_s[cur][0];
      #pragma unroll
      for (int p = 0; p < 4; ++p) {
        __builtin_amdgcn_global_load_lds(gh + p * 2048 + tid * 8, dh + p * 2048 + tid * 8, 16, 0, 0);
        __builtin_amdgcn_global_load_lds(gl + p * 2048 + tid * 8, dl + p * 2048 + tid * 8, 16, 0, 0);
      }
      asm volatile("s_waitcnt vmcnt(8)" ::: "memory");   // chunk c+1 landed
    } else if (c == 6) {
      asm volatile("s_waitcnt vmcnt(0)" ::: "memory");   // chunk 7 landed
    }
    __builtin_amdgcn_sched_barrier(0);
    __builtin_amdgcn_s_barrier();           // buf[(c+1)&1] ready for all
  }

  // merge across lane-halves (same token for lane ^ 32)
  {
    const float ov = __shfl_xor(bv, 32, 64);
    const int oi = __shfl_xor(bi, 32, 64);
    if (ov > bv || (ov == bv && oi < bi)) { bv = ov; bi = oi; }
  }

  // fused output write: lane covers token `tok`, d-range half*64..+64
  {
    const float* er = e32 + (size_t)bi * ND + half * 64;
    float* ob = out + (size_t)bb * ND * NHW + (size_t)(half * 64) * NHW + hw;
    #pragma unroll
    for (int j4 = 0; j4 < 16; ++j4) {
      const float4 ev = *(const float4*)(er + j4 * 4);
      ob[(size_t)(j4 * 4 + 0) * NHW] = ev.x;
      ob[(size_t)(j4 * 4 + 1) * NHW] = ev.y;
      ob[(size_t)(j4 * 4 + 2) * NHW] = ev.z;
      ob[(size_t)(j4 * 4 + 3) * NHW] = ev.w;
    }
  }
}

// ======================================================== fp32 fallback =====
__global__ __launch_bounds__(128) void vq_enorm(const float* __restrict__ e,
                                                float* __restrict__ ensw) {
  const int k = blockIdx.x;
  const int d = threadIdx.x;
  const float v = e[k * ND + d];
  float s = v * v;
  #pragma unroll
  for (int off = 32; off > 0; off >>= 1) s += __shfl_down(s, off, 64);
  __shared__ float tmp[2];
  if ((d & 63) == 0) tmp[d >> 6] = s;
  __syncthreads();
  if (d == 0) ensw[k] = tmp[0] + tmp[1];
}

__global__ __launch_bounds__(256, 2) void vq_main_f32(const float* __restrict__ x,
                                                      const float* __restrict__ e,
                                                      const float* __restrict__ ensw,
                                                      float* __restrict__ out) {
  __shared__ float xs[ND][64];
  __shared__ float esh[ND][64];
  __shared__ float enh[NK];
  __shared__ float red_v[64][17];
  __shared__ int red_i[64][17];
  __shared__ int bidx[64];
  const int tid = threadIdx.x;
  const int b = blockIdx.x >> 6;
  const int hw0 = (blockIdx.x & 63) * 64;
  const float* xb = x + ((size_t)b * ND) * NHW;
  #pragma unroll
  for (int i = 0; i < 8; ++i) {
    const int f = tid + 256 * i;
    const int d = f >> 4, t4 = f & 15;
    const float4 v = *(const float4*)(xb + (size_t)d * NHW + hw0 + 4 * t4);
    *(float4*)&xs[d][4 * t4] = v;
  }
  #pragma unroll
  for (int i = 0; i < 2; ++i) enh[tid + 256 * i] = ensw[tid + 256 * i];
  const int t4 = tid & 15, m = tid >> 4;
  float bvv[4] = {-3.0e38f, -3.0e38f, -3.0e38f, -3.0e38f};
  int bii[4] = {0, 0, 0, 0};
  for (int kc = 0; kc < NK / 64; ++kc) {
    __syncthreads();
    #pragma unroll
    for (int i = 0; i < 8; ++i) {
      const int f = tid + 256 * i;
      const int kk = f & 63, dq = f >> 6;
      const float4 v = *(const float4*)(e + (size_t)(kc * 64 + kk) * ND + 4 * dq);
      esh[4 * dq + 0][kk] = v.x; esh[4 * dq + 1][kk] = v.y;
      esh[4 * dq + 2][kk] = v.z; esh[4 * dq + 3][kk] = v.w;
    }
    __syncthreads();
    float acc[4][4];
    #pragma unroll
    for (int a = 0; a < 4; ++a)
      #pragma unroll
      for (int cc = 0; cc < 4; ++cc) acc[a][cc] = 0.0f;
    #pragma unroll 8
    for (int d = 0; d < 128; ++d) {
      const float4 xv = *(const float4*)&xs[d][4 * t4];
      const float4 ev = *(const float4*)&esh[d][4 * m];
      const float xa[4] = {xv.x, xv.y, xv.z, xv.w};
      const float ea[4] = {ev.x, ev.y, ev.z, ev.w};
      #pragma unroll
      for (int a = 0; a < 4; ++a)
        #pragma unroll
        for (int cc = 0; cc < 4; ++cc) acc[a][cc] = fmaf(xa[a], ea[cc], acc[a][cc]);
    }
    const int kbase = kc * 64 + 4 * m;
    #pragma unroll
    for (int cc = 0; cc < 4; ++cc) {
      const float bias = 0.5f * enh[kbase + cc];
      const int kg = kbase + cc;
      #pragma unroll
      for (int a = 0; a < 4; ++a) {
        const float s = acc[a][cc] - bias;
        if (s > bvv[a] || (s == bvv[a] && kg < bii[a])) { bvv[a] = s; bii[a] = kg; }
      }
    }
  }
  #pragma unroll
  for (int a = 0; a < 4; ++a) { red_v[4 * t4 + a][m] = bvv[a]; red_i[4 * t4 + a][m] = bii[a]; }
  __syncthreads();
  if (tid < 64) {
    float v = red_v[tid][0]; int ix = red_i[tid][0];
    #pragma unroll
    for (int j = 1; j < 16; ++j) {
      const float vj = red_v[tid][j]; const int ij = red_i[tid][j];
      if (vj > v || (vj == v && ij < ix)) { v = vj; ix = ij; }
    }
    bidx[tid] = ix;
  }
  __syncthreads();
  const int t = tid & 63, dgg = tid >> 6;
  const float* er = e + (size_t)bidx[t] * ND;
  float* ob = out + ((size_t)b * ND) * NHW + hw0 + t;
  #pragma unroll
  for (int i = 0; i < 32; ++i) ob[(size_t)(dgg * 32 + i) * NHW] = er[dgg * 32 + i];
}

// --------------------------------------------------------------- launch -----
extern "C" void kernel_launch(void* const* d_in, const int* in_sizes, int n_in,
                              void* d_out, int out_size, void* d_ws, size_t ws_size,
                              hipStream_t stream) {
  const float* x = (const float*)d_in[0];
  const float* e = (const float*)d_in[1];
  float* out = (float*)d_out;
  char* ws = (char*)d_ws;

  if (ws_size >= WS_NEED) {
    f16* ehi = (f16*)(ws + WS_EHI);
    f16* elo = (f16*)(ws + WS_ELO);
    float* ens = (float*)(ws + WS_ENS);
    vq_prep_e<<<32, 256, 0, stream>>>(e, ehi, elo, ens);
    vq_score<<<512, 256, 0, stream>>>(x, ehi, elo, ens, e, out);
  } else {
    float* ensw = (float*)d_ws;
    vq_enorm<<<512, 128, 0, stream>>>(e, ensw);
    vq_main_f32<<<16 * 64, 256, 0, stream>>>(x, e, ensw, out);
  }
}